// Round 4
// baseline (873.817 us; speedup 1.0000x reference)
//
#include <hip/hip_runtime.h>
#include <math.h>

#define NTOK 16384
#define HDIM 2048
#define KNOI 25
#define RPW  4            // rows per wave
#define WPB  4            // waves per block (256 threads)
#define CHUNK 256         // floats of H per chunk
#define NCHUNK (HDIM / CHUNK)   // 8

typedef __attribute__((address_space(3))) unsigned lds_uint;
typedef __attribute__((address_space(1))) const unsigned glob_uint;

// Async global->LDS, 16B per lane, dest = uniform base + lane*16 (HW rule).
__device__ __forceinline__ void stage16(const void* g, void* l) {
    __builtin_amdgcn_global_load_lds((glob_uint*)g, (lds_uint*)l, 16, 0, 0);
}

// Wave64 sum via DPP on the VALU pipe (no LDS traffic). Total lands in lane 63.
// update_dpp needs literal ctrl/rmask -> template parameters.
template <int CTRL, int RMASK>
__device__ __forceinline__ float dpp_add(float v) {
    const int s = __builtin_amdgcn_update_dpp(0, __float_as_int(v), CTRL, RMASK, 0xf, true);
    return v + __int_as_float(s);
}
__device__ __forceinline__ float wave_sum63(float v) {
    v = dpp_add<0x111, 0xf>(v);   // row_shr:1
    v = dpp_add<0x112, 0xf>(v);   // row_shr:2
    v = dpp_add<0x114, 0xf>(v);   // row_shr:4
    v = dpp_add<0x118, 0xf>(v);   // row_shr:8  -> lane15 of each row16 = row sum
    v = dpp_add<0x142, 0xa>(v);   // row_bcast:15 -> rows 1,3
    v = dpp_add<0x143, 0xc>(v);   // row_bcast:31 -> rows 2,3; lane63 = total
    return v;
}

// Block: 4 waves x 4 rows = 16 token rows. Noise chunks double-buffered in LDS
// (staged via global_load_lds while previous chunk computes; ONE barrier/chunk).
// Each ds_read_b128 of a noise float4 feeds 16 FMAs (4 rows). Reductions on
// the VALU pipe via DPP; lane 63 owns the epilogue.
__global__ __launch_bounds__(256, 3) void nce_main(
    const float* __restrict__ input,
    const float* __restrict__ weight,
    const float* __restrict__ bias,
    const float* __restrict__ uni,
    const int* __restrict__ target,
    const int* __restrict__ noise,
    float* __restrict__ out)
{
    __shared__ float4 ldsn[2][KNOI * (CHUNK / 4)];   // 2 x 25.6 KB

    float* pmt = out;
    float* pnt = out + NTOK;
    float* pmn = out + 2 * NTOK;
    float* pnn = out + 2 * NTOK + NTOK * KNOI;

    const int lane = threadIdx.x & 63;
    const int wave = threadIdx.x >> 6;
    int row0 = (blockIdx.x * WPB + wave) * RPW;
    row0 = __builtin_amdgcn_readfirstlane(row0);

    // Uniform metadata -> force SGPR. Byte offsets fit u32 (50257*8192 < 2^32).
    unsigned noffb[KNOI];
#pragma unroll
    for (int k = 0; k < KNOI; ++k)
        noffb[k] = __builtin_amdgcn_readfirstlane((unsigned)noise[k] * (unsigned)(HDIM * 4));

    unsigned toffb[RPW], ioffb[RPW];
#pragma unroll
    for (int r = 0; r < RPW; ++r) {
        toffb[r] = __builtin_amdgcn_readfirstlane((unsigned)target[row0 + r] * (unsigned)(HDIM * 4));
        ioffb[r] = (unsigned)(row0 + r) * (unsigned)(HDIM * 4);
    }

    const char* wb = (const char*)weight;
    const char* ib = (const char*)input;
    const unsigned laneoff = (unsigned)lane * 16u;

    float acc[RPW][KNOI];
    float acct[RPW];
#pragma unroll
    for (int r = 0; r < RPW; ++r) {
        acct[r] = 0.f;
#pragma unroll
        for (int k = 0; k < KNOI; ++k) acc[r][k] = 0.f;
    }

    // Prologue: stage chunk 0 into buffer 0 (wave w stages rows w, w+4, ...).
#pragma unroll
    for (int j = 0; j < 7; ++j) {
        const int k = j * WPB + wave;
        if (k < KNOI)
            stage16(wb + noffb[k] + laneoff, &ldsn[0][k * (CHUNK / 4)]);
    }
    __syncthreads();

#pragma unroll 2
    for (int c = 0; c < NCHUNK; ++c) {
        const int cur = c & 1;
        const unsigned cb = (unsigned)c * (unsigned)(CHUNK * 4) + laneoff;

        // Issue this chunk's input/target loads first (HBM head start)...
        float4 inv[RPW], tgv[RPW];
#pragma unroll
        for (int r = 0; r < RPW; ++r) {
            inv[r] = *(const float4*)(ib + ioffb[r] + cb);
            tgv[r] = *(const float4*)(wb + toffb[r] + cb);
        }

        // ...then stage NEXT chunk's noise into the other buffer (hidden
        // behind this chunk's compute; drained at the single barrier below).
        if (c + 1 < NCHUNK) {
            const unsigned nb = (unsigned)(c + 1) * (unsigned)(CHUNK * 4) + laneoff;
#pragma unroll
            for (int j = 0; j < 7; ++j) {
                const int k = j * WPB + wave;
                if (k < KNOI)
                    stage16(wb + noffb[k] + nb, &ldsn[cur ^ 1][k * (CHUNK / 4)]);
            }
        }

        // Compute: target dots + 25 noise rows x 4 token rows.
#pragma unroll
        for (int r = 0; r < RPW; ++r)
            acct[r] += inv[r].x * tgv[r].x + inv[r].y * tgv[r].y +
                       inv[r].z * tgv[r].z + inv[r].w * tgv[r].w;
#pragma unroll
        for (int k = 0; k < KNOI; ++k) {
            const float4 w = ldsn[cur][k * (CHUNK / 4) + lane];   // ds_read_b128
#pragma unroll
            for (int r = 0; r < RPW; ++r)
                acc[r][k] += inv[r].x * w.x + inv[r].y * w.y +
                             inv[r].z * w.z + inv[r].w * w.w;
        }

        __syncthreads();   // drains next-chunk staging; fences buffer reuse
    }

    // Reduce all 104 accumulators on the VALU pipe; totals land in lane 63.
#pragma unroll
    for (int r = 0; r < RPW; ++r) {
        acct[r] = wave_sum63(acct[r]);
#pragma unroll
        for (int k = 0; k < KNOI; ++k)
            acc[r][k] = wave_sum63(acc[r][k]);
    }

    // Epilogue: lane 63 stores its wave's 4 rows (indices recovered from
    // byte offsets: off = idx*8192 -> idx = off>>13).
    if (lane == 63) {
#pragma unroll
        for (int r = 0; r < RPW; ++r) {
            const int row = row0 + r;
            const int tk = (int)(toffb[r] >> 13);
            pmt[row] = expf(acct[r] + bias[tk]);
            pnt[row] = uni[tk];
#pragma unroll
            for (int k = 0; k < KNOI; ++k) {
                const int nk = (int)(noffb[k] >> 13);
                pmn[row * KNOI + k] = expf(acc[r][k] + bias[nk]);
                pnn[row * KNOI + k] = uni[nk];
            }
        }
    }
}

extern "C" void kernel_launch(void* const* d_in, const int* in_sizes, int n_in,
                              void* d_out, int out_size, void* d_ws, size_t ws_size,
                              hipStream_t stream) {
    const float* input  = (const float*)d_in[0];
    const float* weight = (const float*)d_in[1];
    const float* bias   = (const float*)d_in[2];
    const float* uni    = (const float*)d_in[3];
    const int*   target = (const int*)d_in[4];
    const int*   noise  = (const int*)d_in[5];
    float* out = (float*)d_out;

    const dim3 grid(NTOK / (WPB * RPW));   // 1024 blocks
    const dim3 block(256);
    hipLaunchKernelGGL(nce_main, grid, block, 0, stream,
                       input, weight, bias, uni, target, noise, out);
}